// Round 2
// baseline (220.307 us; speedup 1.0000x reference)
//
#include <hip/hip_runtime.h>
#include <hip/hip_bf16.h>

typedef __attribute__((ext_vector_type(4))) float floatx4;
typedef __attribute__((ext_vector_type(8))) short shortx8;

// ---------------- compile-time DWT matrix M [84][64] ----------------
// db4 analysis filters, TRUE-convolution orientation:
// y[m] = sum_i F[i] * xp[2m + 7 - i], xp reflect-padded (left pad = 6 each level)
constexpr float CLO[8] = {
    -0.010597401784997278f, 0.032883011666982945f,
     0.030841381835986965f, -0.18703481171888114f,
    -0.02798376941698385f,  0.6308807679295904f,
     0.7148465705525415f,   0.23037781330885523f};
constexpr float CHI[8] = {
    -0.23037781330885523f,  0.7148465705525415f,
    -0.6308807679295904f,  -0.02798376941698385f,
     0.18703481171888114f,  0.030841381835986965f,
     0.032883011666982945f, -0.010597401784997278f};

template <int N, int OUT>
constexpr void afb_c(const float* x, float* lo, float* hi) {
  for (int m = 0; m < OUT; ++m) {
    float aL = 0.f, aH = 0.f;
    for (int i = 0; i < 8; ++i) {
      int s = 2 * m + 1 - i;              // 2m + 7 - i - 6
      s = (s < 0) ? -s : s;               // reflect (no edge repeat)
      s = (s >= N) ? (2 * N - 2 - s) : s;
      aL += CLO[i] * x[s];
      aH += CHI[i] * x[s];
    }
    lo[m] = aL; hi[m] = aH;
  }
}

struct MTab { float v[84][64]; };

constexpr MTab make_M() {
  MTab t{};
  for (int c = 0; c < 64; ++c) {
    float sig[64] = {};
    sig[c] = 1.f;
    float lo1[35] = {}, hi1[35] = {}, lo2[21] = {}, hi2[21] = {};
    float lo3[14] = {}, hi3[14] = {};
    afb_c<64, 35>(sig, lo1, hi1);
    afb_c<35, 21>(lo1, lo2, hi2);
    afb_c<21, 14>(lo2, lo3, hi3);
    for (int m = 0; m < 14; ++m) t.v[m][c]      = lo3[m];
    for (int m = 0; m < 35; ++m) t.v[14 + m][c] = hi1[m];
    for (int m = 0; m < 21; ++m) t.v[49 + m][c] = hi2[m];
    for (int m = 0; m < 14; ++m) t.v[70 + m][c] = hi3[m];
  }
  return t;
}

__device__ __constant__ MTab M_TAB = make_M();

__device__ __forceinline__ unsigned short f2bf_rne(float f) {
  unsigned u = __builtin_bit_cast(unsigned, f);
  unsigned r = (u + 0x7FFFu + ((u >> 16) & 1u)) >> 16;
  return (unsigned short)r;
}

// ---------------- W2[k][tp*64+hw] = sum_t M[t][tp] * conv_w[k][t][hw] (bf16) --
// grid (64, 4): blockIdx.x = k, blockIdx.y = 16-wide tp slice.
__global__ __launch_bounds__(256) void build_w2_kernel(
    const float* __restrict__ cw, unsigned short* __restrict__ W2) {
  __shared__ float Cl[84 * 64];
  const int k = blockIdx.x;
  const float* cwk = cw + (size_t)k * (84 * 64);
  for (int idx = threadIdx.x; idx < 84 * 64; idx += 256) Cl[idx] = cwk[idx];
  __syncthreads();
  const int tp  = blockIdx.y * 16 + (threadIdx.x >> 4);
  const int hw0 = (threadIdx.x & 15) * 4;
  float a0 = 0.f, a1 = 0.f, a2 = 0.f, a3 = 0.f;
#pragma unroll 4
  for (int t = 0; t < 84; ++t) {
    const float mv = M_TAB.v[t][tp];
    const float4 cv = *(const float4*)&Cl[t * 64 + hw0];
    a0 = fmaf(mv, cv.x, a0);
    a1 = fmaf(mv, cv.y, a1);
    a2 = fmaf(mv, cv.z, a2);
    a3 = fmaf(mv, cv.w, a3);
  }
  uint2 pk;
  pk.x = (unsigned)f2bf_rne(a0) | ((unsigned)f2bf_rne(a1) << 16);
  pk.y = (unsigned)f2bf_rne(a2) | ((unsigned)f2bf_rne(a3) << 16);
  *(uint2*)(W2 + (size_t)k * 4096 + tp * 64 + hw0) = pk;
}

// ---------------- GEMM: out[8192][64] = leaky(A[8192][4096]*W2[64][4096]^T + b)
// No LDS staging, no K-loop barriers. Both operands loaded straight from
// global in MFMA fragment layout (A frag: row = lane&15, k = kg*8..+7 where
// kg = lane>>4 — validated by the round-0 kernel). A converted to bf16 in
// registers. W2 (512 KB) is L2-resident, so its fragment re-reads are L2
// traffic. Split-K x4 inside the block (one wave per K-quarter), partial
// sums reduced through 16 KB LDS at the end.
#define KQ_LEN 1024   // 4096 / 4 k-quarters
#define KCHUNK 32

__global__ __launch_bounds__(256, 2) void gemm_kernel(
    const float* __restrict__ A, const unsigned short* __restrict__ W2,
    const float* __restrict__ bias, float* __restrict__ out) {
  __shared__ float part[4 * 64 * 16];  // [kq][lane][nt*4+r]  = 16 KB

  const int tid  = threadIdx.x;
  const int lane = tid & 63;
  const int kq   = tid >> 6;          // 0..3: this wave's K-quarter
  const int frow = lane & 15;
  const int kg   = lane >> 4;         // 0..3: k-group within chunk

  const float* aptr =
      A + (size_t)(blockIdx.x * 16 + frow) * 4096 + kq * KQ_LEN + kg * 8;
  const unsigned short* bptr =
      W2 + (size_t)frow * 4096 + kq * KQ_LEN + kg * 8;

  floatx4 acc0 = {0.f, 0.f, 0.f, 0.f};
  floatx4 acc1 = {0.f, 0.f, 0.f, 0.f};
  floatx4 acc2 = {0.f, 0.f, 0.f, 0.f};
  floatx4 acc3 = {0.f, 0.f, 0.f, 0.f};

#pragma unroll 2
  for (int i = 0; i < KQ_LEN / KCHUNK; ++i) {
    const int off = i * KCHUNK;
    float4 a0 = *(const float4*)(aptr + off);
    float4 a1 = *(const float4*)(aptr + off + 4);
    uint4 bv0 = *(const uint4*)(bptr + off);                // n rows  0..15
    uint4 bv1 = *(const uint4*)(bptr + 16 * 4096 + off);    // n rows 16..31
    uint4 bv2 = *(const uint4*)(bptr + 32 * 4096 + off);    // n rows 32..47
    uint4 bv3 = *(const uint4*)(bptr + 48 * 4096 + off);    // n rows 48..63
    shortx8 af;
    af[0] = (short)f2bf_rne(a0.x); af[1] = (short)f2bf_rne(a0.y);
    af[2] = (short)f2bf_rne(a0.z); af[3] = (short)f2bf_rne(a0.w);
    af[4] = (short)f2bf_rne(a1.x); af[5] = (short)f2bf_rne(a1.y);
    af[6] = (short)f2bf_rne(a1.z); af[7] = (short)f2bf_rne(a1.w);
    acc0 = __builtin_amdgcn_mfma_f32_16x16x32_bf16(
        af, __builtin_bit_cast(shortx8, bv0), acc0, 0, 0, 0);
    acc1 = __builtin_amdgcn_mfma_f32_16x16x32_bf16(
        af, __builtin_bit_cast(shortx8, bv1), acc1, 0, 0, 0);
    acc2 = __builtin_amdgcn_mfma_f32_16x16x32_bf16(
        af, __builtin_bit_cast(shortx8, bv2), acc2, 0, 0, 0);
    acc3 = __builtin_amdgcn_mfma_f32_16x16x32_bf16(
        af, __builtin_bit_cast(shortx8, bv3), acc3, 0, 0, 0);
  }

  // stash partials: part[(kq*64+lane)*16 + nt*4 + r]
  float* pp = &part[(kq * 64 + lane) * 16];
  *(floatx4*)(pp + 0)  = acc0;
  *(floatx4*)(pp + 4)  = acc1;
  *(floatx4*)(pp + 8)  = acc2;
  *(floatx4*)(pp + 12) = acc3;
  __syncthreads();

  // epilogue: thread -> (row = tid>>4, 4 cols = (tid&15)*4 ..); sum 4 kq parts.
  // C layout (validated R0): out row = (lane>>4)*4 + r, col = nt*16 + (lane&15)
  const int erow = tid >> 4;
  const int ecg  = (tid & 15) * 4;
  const int nt   = ecg >> 4;
  const int rr   = erow & 3;
  float4 res;
  float* rp = (float*)&res;
#pragma unroll
  for (int j = 0; j < 4; ++j) {
    const int c = ecg + j;
    const int l = ((erow >> 2) << 4) | (c & 15);
    float s = 0.f;
#pragma unroll
    for (int q = 0; q < 4; ++q) s += part[(q * 64 + l) * 16 + nt * 4 + rr];
    const float v = s + bias[c];
    rp[j] = (v >= 0.f) ? v : 0.001f * v;
  }
  *(float4*)(out + (size_t)(blockIdx.x * 16 + erow) * 64 + ecg) = res;
}

extern "C" void kernel_launch(void* const* d_in, const int* in_sizes, int n_in,
                              void* d_out, int out_size, void* d_ws, size_t ws_size,
                              hipStream_t stream) {
  const float* x      = (const float*)d_in[0];  // [8192,1,64,8,8]
  const float* conv_w = (const float*)d_in[1];  // [64,84,8,8]
  const float* conv_b = (const float*)d_in[2];  // [64]
  float* out = (float*)d_out;                   // [8192,64]

  unsigned short* W2 = (unsigned short*)d_ws;   // 64*4096 bf16 = 512 KB

  build_w2_kernel<<<dim3(64, 4), 256, 0, stream>>>(conv_w, W2);
  gemm_kernel<<<512, 256, 0, stream>>>(x, W2, conv_b, out);
}

// Round 3
// 211.204 us; speedup vs baseline: 1.0431x; 1.0431x over previous
//
#include <hip/hip_runtime.h>
#include <hip/hip_bf16.h>

typedef __attribute__((ext_vector_type(4))) float floatx4;
typedef __attribute__((ext_vector_type(8))) short shortx8;

// ---------------- compile-time DWT matrix M [84][64] ----------------
constexpr float CLO[8] = {
    -0.010597401784997278f, 0.032883011666982945f,
     0.030841381835986965f, -0.18703481171888114f,
    -0.02798376941698385f,  0.6308807679295904f,
     0.7148465705525415f,   0.23037781330885523f};
constexpr float CHI[8] = {
    -0.23037781330885523f,  0.7148465705525415f,
    -0.6308807679295904f,  -0.02798376941698385f,
     0.18703481171888114f,  0.030841381835986965f,
     0.032883011666982945f, -0.010597401784997278f};

template <int N, int OUT>
constexpr void afb_c(const float* x, float* lo, float* hi) {
  for (int m = 0; m < OUT; ++m) {
    float aL = 0.f, aH = 0.f;
    for (int i = 0; i < 8; ++i) {
      int s = 2 * m + 1 - i;              // 2m + 7 - i - 6 (left pad 6)
      s = (s < 0) ? -s : s;               // reflect (no edge repeat)
      s = (s >= N) ? (2 * N - 2 - s) : s;
      aL += CLO[i] * x[s];
      aH += CHI[i] * x[s];
    }
    lo[m] = aL; hi[m] = aH;
  }
}

struct MTab { float v[84][64]; };

constexpr MTab make_M() {
  MTab t{};
  for (int c = 0; c < 64; ++c) {
    float sig[64] = {};
    sig[c] = 1.f;
    float lo1[35] = {}, hi1[35] = {}, lo2[21] = {}, hi2[21] = {};
    float lo3[14] = {}, hi3[14] = {};
    afb_c<64, 35>(sig, lo1, hi1);
    afb_c<35, 21>(lo1, lo2, hi2);
    afb_c<21, 14>(lo2, lo3, hi3);
    for (int m = 0; m < 14; ++m) t.v[m][c]      = lo3[m];
    for (int m = 0; m < 35; ++m) t.v[14 + m][c] = hi1[m];
    for (int m = 0; m < 21; ++m) t.v[49 + m][c] = hi2[m];
    for (int m = 0; m < 14; ++m) t.v[70 + m][c] = hi3[m];
  }
  return t;
}

__device__ __constant__ MTab M_TAB = make_M();

__device__ __forceinline__ unsigned short f2bf_rne(float f) {
  unsigned u = __builtin_bit_cast(unsigned, f);
  unsigned r = (u + 0x7FFFu + ((u >> 16) & 1u)) >> 16;
  return (unsigned short)r;
}

// ---------------- W2[k][tp*64+hw] = sum_t M[t][tp]*conv_w[k][t][hw] (bf16) ---
__global__ __launch_bounds__(256) void build_w2_kernel(
    const float* __restrict__ cw, unsigned short* __restrict__ W2) {
  __shared__ float Cl[84 * 64];
  const int k = blockIdx.x;
  const float* cwk = cw + (size_t)k * (84 * 64);
  for (int idx = threadIdx.x; idx < 84 * 64; idx += 256) Cl[idx] = cwk[idx];
  __syncthreads();
  const int tp  = blockIdx.y * 16 + (threadIdx.x >> 4);
  const int hw0 = (threadIdx.x & 15) * 4;
  float a0 = 0.f, a1 = 0.f, a2 = 0.f, a3 = 0.f;
#pragma unroll 4
  for (int t = 0; t < 84; ++t) {
    const float mv = M_TAB.v[t][tp];
    const float4 cv = *(const float4*)&Cl[t * 64 + hw0];
    a0 = fmaf(mv, cv.x, a0);
    a1 = fmaf(mv, cv.y, a1);
    a2 = fmaf(mv, cv.z, a2);
    a3 = fmaf(mv, cv.w, a3);
  }
  uint2 pk;
  pk.x = (unsigned)f2bf_rne(a0) | ((unsigned)f2bf_rne(a1) << 16);
  pk.y = (unsigned)f2bf_rne(a2) | ((unsigned)f2bf_rne(a3) << 16);
  *(uint2*)(W2 + (size_t)k * 4096 + tp * 64 + hw0) = pk;
}

// ---------------- split-K GEMM, B stationary in LDS -------------------------
// grid 512: rowTile = bx>>2 (64 rows each), kq = bx&3 (1024-k quarter).
// Block 512 thr = 8 waves: mt = w&3 (16-row tile), ks = w>>2 (512-k half).
// K-loop: 2 global A loads + 4 ds_read_b128 + 4 MFMA per 32-k chunk; NO
// barriers, no global B traffic. Partials -> ws, reduced by reduce_kernel.
#define BLDK 1032  // 1024 + 8 pad: row stride 516 dw == 4 mod 32 -> balanced banks

__global__ __launch_bounds__(512, 2) void gemm_partial(
    const float* __restrict__ A, const unsigned short* __restrict__ W2,
    float* __restrict__ pws) {
  __shared__ alignas(16) char smem[64 * BLDK * 2];  // 129 KB, reused at epilogue
  short* Bs = (short*)smem;
  float* part = (float*)smem;

  const int tid = threadIdx.x;
  const int rowTile = blockIdx.x >> 2;
  const int kq = blockIdx.x & 3;

  // stage B slice (once): W2[n][kq*1024 + c] -> Bs[n*BLDK + c]
#pragma unroll
  for (int j = 0; j < 16; ++j) {
    const int idx16 = tid + j * 512;       // 16B chunk id
    const int n = idx16 >> 7;
    const int c = (idx16 & 127) * 8;
    uint4 g = *(const uint4*)(W2 + (size_t)n * 4096 + kq * 1024 + c);
    *(uint4*)&Bs[n * BLDK + c] = g;
  }
  __syncthreads();

  const int lane = tid & 63;
  const int w = tid >> 6;
  const int mt = w & 3;
  const int ks = w >> 2;
  const int frow = lane & 15;
  const int kg = lane >> 4;

  const float* aptr = A + (size_t)(rowTile * 64 + mt * 16 + frow) * 4096 +
                      kq * 1024 + ks * 512 + kg * 8;
  const short* bbase = Bs + ks * 512 + kg * 8;

  floatx4 acc0 = {0.f, 0.f, 0.f, 0.f};
  floatx4 acc1 = {0.f, 0.f, 0.f, 0.f};
  floatx4 acc2 = {0.f, 0.f, 0.f, 0.f};
  floatx4 acc3 = {0.f, 0.f, 0.f, 0.f};

  // depth-2 register prefetch of A; B comes from LDS (short latency)
  float4 a0c = *(const float4*)(aptr);
  float4 a1c = *(const float4*)(aptr + 4);
  float4 a0n = *(const float4*)(aptr + 32);
  float4 a1n = *(const float4*)(aptr + 36);

  for (int i = 0; i < 16; ++i) {
    const float4 c0 = a0c, c1 = a1c;
    a0c = a0n; a1c = a1n;
    if (i + 2 < 16) {
      a0n = *(const float4*)(aptr + (i + 2) * 32);
      a1n = *(const float4*)(aptr + (i + 2) * 32 + 4);
    }
    shortx8 af;
    af[0] = (short)f2bf_rne(c0.x); af[1] = (short)f2bf_rne(c0.y);
    af[2] = (short)f2bf_rne(c0.z); af[3] = (short)f2bf_rne(c0.w);
    af[4] = (short)f2bf_rne(c1.x); af[5] = (short)f2bf_rne(c1.y);
    af[6] = (short)f2bf_rne(c1.z); af[7] = (short)f2bf_rne(c1.w);
    const short* bp = bbase + i * 32;
    shortx8 bf0 = *(const shortx8*)(bp + (0 * 16 + frow) * BLDK);
    shortx8 bf1 = *(const shortx8*)(bp + (1 * 16 + frow) * BLDK);
    shortx8 bf2 = *(const shortx8*)(bp + (2 * 16 + frow) * BLDK);
    shortx8 bf3 = *(const shortx8*)(bp + (3 * 16 + frow) * BLDK);
    acc0 = __builtin_amdgcn_mfma_f32_16x16x32_bf16(af, bf0, acc0, 0, 0, 0);
    acc1 = __builtin_amdgcn_mfma_f32_16x16x32_bf16(af, bf1, acc1, 0, 0, 0);
    acc2 = __builtin_amdgcn_mfma_f32_16x16x32_bf16(af, bf2, acc2, 0, 0, 0);
    acc3 = __builtin_amdgcn_mfma_f32_16x16x32_bf16(af, bf3, acc3, 0, 0, 0);
  }

  __syncthreads();  // everyone done reading Bs; reuse region for partials
  float* pp = part + (w * 64 + lane) * 16;
  *(floatx4*)(pp + 0)  = acc0;
  *(floatx4*)(pp + 4)  = acc1;
  *(floatx4*)(pp + 8)  = acc2;
  *(floatx4*)(pp + 12) = acc3;
  __syncthreads();

  // gather ks=0 + ks=1, store partial [kq][row][n] coalesced
  // C layout (validated): row = (lane>>4)*4 + reg, col = nt*16 + (lane&15)
  const int o = tid * 8;
  const int row = o >> 6;
  const int cb = o & 63;
  const int mt2 = row >> 4, rw = row & 15;
  const int lh = (rw >> 2) << 4, r = rw & 3;
  float vals[8];
#pragma unroll
  for (int jj = 0; jj < 8; ++jj) {
    const int c = cb + jj;
    const int l = lh | (c & 15);
    const int j = ((c >> 4) << 2) | r;
    vals[jj] = part[(mt2 * 64 + l) * 16 + j] + part[((mt2 + 4) * 64 + l) * 16 + j];
  }
  float* dst = pws + (size_t)kq * 524288 + (size_t)(rowTile * 64 + row) * 64 + cb;
  *(float4*)(dst + 0) = *(float4*)&vals[0];
  *(float4*)(dst + 4) = *(float4*)&vals[4];
}

// ---------------- reduce 4 partials + bias + LeakyReLU ----------------------
__global__ __launch_bounds__(256) void reduce_kernel(
    const float* __restrict__ pws, const float* __restrict__ bias,
    float* __restrict__ out) {
  const int f = (blockIdx.x * 256 + threadIdx.x) * 4;
  float4 s = *(const float4*)(pws + f);
#pragma unroll
  for (int q = 1; q < 4; ++q) {
    const float4 p = *(const float4*)(pws + (size_t)q * 524288 + f);
    s.x += p.x; s.y += p.y; s.z += p.z; s.w += p.w;
  }
  const float4 bv = *(const float4*)(bias + (f & 63));
  float4 r;
  r.x = s.x + bv.x; r.y = s.y + bv.y; r.z = s.z + bv.z; r.w = s.w + bv.w;
  r.x = (r.x >= 0.f) ? r.x : 0.001f * r.x;
  r.y = (r.y >= 0.f) ? r.y : 0.001f * r.y;
  r.z = (r.z >= 0.f) ? r.z : 0.001f * r.z;
  r.w = (r.w >= 0.f) ? r.w : 0.001f * r.w;
  *(float4*)(out + f) = r;
}

extern "C" void kernel_launch(void* const* d_in, const int* in_sizes, int n_in,
                              void* d_out, int out_size, void* d_ws, size_t ws_size,
                              hipStream_t stream) {
  const float* x      = (const float*)d_in[0];  // [8192,1,64,8,8]
  const float* conv_w = (const float*)d_in[1];  // [64,84,8,8]
  const float* conv_b = (const float*)d_in[2];  // [64]
  float* out = (float*)d_out;                   // [8192,64]

  float* pws = (float*)d_ws;                                      // 8 MB partials
  unsigned short* W2 = (unsigned short*)((char*)d_ws + (8 << 20)); // 512 KB

  build_w2_kernel<<<dim3(64, 4), 256, 0, stream>>>(conv_w, W2);
  gemm_partial<<<512, 512, 0, stream>>>(x, W2, pws);
  reduce_kernel<<<512, 256, 0, stream>>>(pws, conv_b, out);
}

// Round 4
// 204.002 us; speedup vs baseline: 1.0799x; 1.0353x over previous
//
#include <hip/hip_runtime.h>
#include <hip/hip_bf16.h>

typedef __attribute__((ext_vector_type(4))) float floatx4;
typedef __attribute__((ext_vector_type(8))) short shortx8;

// ---------------- compile-time DWT matrix M [84][64] ----------------
// db4 analysis filters, TRUE-convolution orientation:
// y[m] = sum_i F[i] * xp[2m + 7 - i], xp reflect-padded (left pad = 6 / level)
constexpr float CLO[8] = {
    -0.010597401784997278f, 0.032883011666982945f,
     0.030841381835986965f, -0.18703481171888114f,
    -0.02798376941698385f,  0.6308807679295904f,
     0.7148465705525415f,   0.23037781330885523f};
constexpr float CHI[8] = {
    -0.23037781330885523f,  0.7148465705525415f,
    -0.6308807679295904f,  -0.02798376941698385f,
     0.18703481171888114f,  0.030841381835986965f,
     0.032883011666982945f, -0.010597401784997278f};

template <int N, int OUT>
constexpr void afb_c(const float* x, float* lo, float* hi) {
  for (int m = 0; m < OUT; ++m) {
    float aL = 0.f, aH = 0.f;
    for (int i = 0; i < 8; ++i) {
      int s = 2 * m + 1 - i;              // 2m + 7 - i - 6
      s = (s < 0) ? -s : s;               // reflect (no edge repeat)
      s = (s >= N) ? (2 * N - 2 - s) : s;
      aL += CLO[i] * x[s];
      aH += CHI[i] * x[s];
    }
    lo[m] = aL; hi[m] = aH;
  }
}

struct MTab { float v[84][64]; };

constexpr MTab make_M() {
  MTab t{};
  for (int c = 0; c < 64; ++c) {
    float sig[64] = {};
    sig[c] = 1.f;
    float lo1[35] = {}, hi1[35] = {}, lo2[21] = {}, hi2[21] = {};
    float lo3[14] = {}, hi3[14] = {};
    afb_c<64, 35>(sig, lo1, hi1);
    afb_c<35, 21>(lo1, lo2, hi2);
    afb_c<21, 14>(lo2, lo3, hi3);
    for (int m = 0; m < 14; ++m) t.v[m][c]      = lo3[m];
    for (int m = 0; m < 35; ++m) t.v[14 + m][c] = hi1[m];
    for (int m = 0; m < 21; ++m) t.v[49 + m][c] = hi2[m];
    for (int m = 0; m < 14; ++m) t.v[70 + m][c] = hi3[m];
  }
  return t;
}

__device__ __constant__ MTab M_TAB = make_M();

__device__ __forceinline__ unsigned short f2bf_rne(float f) {
  unsigned u = __builtin_bit_cast(unsigned, f);
  unsigned r = (u + 0x7FFFu + ((u >> 16) & 1u)) >> 16;
  return (unsigned short)r;
}

// ---------------- W2[k][tp*64+hw] = sum_t M[t][tp]*conv_w[k][t][hw] (bf16) ---
// grid (64, 4): blockIdx.x = k, blockIdx.y = 16-wide tp slice.
__global__ __launch_bounds__(256) void build_w2_kernel(
    const float* __restrict__ cw, unsigned short* __restrict__ W2) {
  __shared__ float Cl[84 * 64];
  const int k = blockIdx.x;
  const float* cwk = cw + (size_t)k * (84 * 64);
  for (int idx = threadIdx.x; idx < 84 * 64; idx += 256) Cl[idx] = cwk[idx];
  __syncthreads();
  const int tp  = blockIdx.y * 16 + (threadIdx.x >> 4);
  const int hw0 = (threadIdx.x & 15) * 4;
  float a0 = 0.f, a1 = 0.f, a2 = 0.f, a3 = 0.f;
#pragma unroll 4
  for (int t = 0; t < 84; ++t) {
    const float mv = M_TAB.v[t][tp];
    const float4 cv = *(const float4*)&Cl[t * 64 + hw0];
    a0 = fmaf(mv, cv.x, a0);
    a1 = fmaf(mv, cv.y, a1);
    a2 = fmaf(mv, cv.z, a2);
    a3 = fmaf(mv, cv.w, a3);
  }
  uint2 pk;
  pk.x = (unsigned)f2bf_rne(a0) | ((unsigned)f2bf_rne(a1) << 16);
  pk.y = (unsigned)f2bf_rne(a2) | ((unsigned)f2bf_rne(a3) << 16);
  *(uint2*)(W2 + (size_t)k * 4096 + tp * 64 + hw0) = pk;
}

// ---------------- GEMM (R0 structure, the best-measured) --------------------
// out[8192][64] = leaky(A[8192][4096] * W2[64][4096]^T + b)
#define BM 32
#define BN 64
#define BK 128
#define LDK 136   // +8 bf16 pad: frag-read row stride 272B -> 2-way bank alias (free)
#define NITER 32  // 4096 / BK

__global__ __launch_bounds__(512) void gemm_kernel(
    const float* __restrict__ A, const unsigned short* __restrict__ W2,
    const float* __restrict__ bias, float* __restrict__ out) {
  __shared__ alignas(16) short As[2][BM * LDK];
  __shared__ alignas(16) short Bs[2][BN * LDK];

  const int tid = threadIdx.x;
  const int b0 = blockIdx.x * BM;

  // staging maps
  const int ar = tid >> 4;             // 0..31  (A row in tile)
  const int ac = (tid & 15) * 8;       // 0..120 (A col in chunk, 8 floats)
  const int bn = tid >> 3;             // 0..63  (W2 row)
  const int bc = (tid & 7) * 16;       // 0..112 (16 bf16)

  const float* aptr = A + (size_t)(b0 + ar) * 4096 + ac;
  const unsigned short* bptr = W2 + (size_t)bn * 4096 + bc;

  // mfma tile assignment: 8 waves -> 2 mtiles x 4 ntiles of 16x16
  const int lane = tid & 63;
  const int wave = tid >> 6;
  const int mt = wave >> 2;
  const int nt = wave & 3;
  const int frow = lane & 15;
  const int fk = (lane >> 4) * 8;

  floatx4 acc = {0.f, 0.f, 0.f, 0.f};

  // depth-2 register prefetch (chunks 0 and 1)
  float4 a0_0 = *(const float4*)(aptr + 0);
  float4 a1_0 = *(const float4*)(aptr + 4);
  uint4  b0_0 = *(const uint4*)(bptr + 0);
  uint4  b1_0 = *(const uint4*)(bptr + 8);
  float4 a0_1 = *(const float4*)(aptr + BK);
  float4 a1_1 = *(const float4*)(aptr + BK + 4);
  uint4  b0_1 = *(const uint4*)(bptr + BK);
  uint4  b1_1 = *(const uint4*)(bptr + BK + 8);

  // Raw barrier: lgkmcnt(0) orders this wave's LDS writes AND drains its
  // previous-step ds_reads, but vmcnt is NOT drained, so the depth-2 global
  // prefetches stay in flight across the barrier.
#define GSTEP(S, I)                                                          \
  do {                                                                       \
    shortx8 av;                                                              \
    av[0] = (short)f2bf_rne(a0_##S.x); av[1] = (short)f2bf_rne(a0_##S.y);    \
    av[2] = (short)f2bf_rne(a0_##S.z); av[3] = (short)f2bf_rne(a0_##S.w);    \
    av[4] = (short)f2bf_rne(a1_##S.x); av[5] = (short)f2bf_rne(a1_##S.y);    \
    av[6] = (short)f2bf_rne(a1_##S.z); av[7] = (short)f2bf_rne(a1_##S.w);    \
    *(shortx8*)&As[S][ar * LDK + ac] = av;                                   \
    *(uint4*)&Bs[S][bn * LDK + bc] = b0_##S;                                 \
    *(uint4*)&Bs[S][bn * LDK + bc + 8] = b1_##S;                             \
    __asm__ __volatile__("s_waitcnt lgkmcnt(0)\n\ts_barrier" ::: "memory");  \
    if ((I) + 2 < NITER) {                                                   \
      const int c2 = ((I) + 2) * BK;                                         \
      a0_##S = *(const float4*)(aptr + c2);                                  \
      a1_##S = *(const float4*)(aptr + c2 + 4);                              \
      b0_##S = *(const uint4*)(bptr + c2);                                   \
      b1_##S = *(const uint4*)(bptr + c2 + 8);                               \
    }                                                                        \
    _Pragma("unroll")                                                        \
    for (int kk = 0; kk < 4; ++kk) {                                         \
      shortx8 af = *(const shortx8*)&As[S][(mt * 16 + frow) * LDK + kk * 32 + fk]; \
      shortx8 bf = *(const shortx8*)&Bs[S][(nt * 16 + frow) * LDK + kk * 32 + fk]; \
      acc = __builtin_amdgcn_mfma_f32_16x16x32_bf16(af, bf, acc, 0, 0, 0);   \
    }                                                                        \
  } while (0)

  for (int i = 0; i < NITER; i += 2) {
    GSTEP(0, i);
    GSTEP(1, i + 1);
  }
#undef GSTEP

  // epilogue: D layout col = lane&15 (n), row = (lane>>4)*4 + r (m)
  const int ocol = nt * 16 + (lane & 15);
  const int orow0 = b0 + mt * 16 + (lane >> 4) * 4;
  const float bv = bias[ocol];
#pragma unroll
  for (int r = 0; r < 4; ++r) {
    float v = acc[r] + bv;
    out[(size_t)(orow0 + r) * 64 + ocol] = (v >= 0.f) ? v : 1.0e-3f * v;
  }
}

extern "C" void kernel_launch(void* const* d_in, const int* in_sizes, int n_in,
                              void* d_out, int out_size, void* d_ws, size_t ws_size,
                              hipStream_t stream) {
  const float* x      = (const float*)d_in[0];  // [8192,1,64,8,8]
  const float* conv_w = (const float*)d_in[1];  // [64,84,8,8]
  const float* conv_b = (const float*)d_in[2];  // [64]
  float* out = (float*)d_out;                   // [8192,64]

  unsigned short* W2 = (unsigned short*)d_ws;   // 64*4096 bf16 = 512 KB

  build_w2_kernel<<<dim3(64, 4), 256, 0, stream>>>(conv_w, W2);
  gemm_kernel<<<256, 512, 0, stream>>>(x, W2, conv_b, out);
}